// Round 1
// baseline (293.949 us; speedup 1.0000x reference)
//
#include <hip/hip_runtime.h>

#define H_ 16
#define D_ 128
#define CAPF 20.0f

typedef __attribute__((ext_vector_type(4))) float f32x4;
typedef __attribute__((ext_vector_type(8))) short bf8_t;  // 8 bf16 in 4 VGPRs

__device__ __forceinline__ short f2bf(float x) {
  unsigned u = __builtin_bit_cast(unsigned, x);
  u += 0x7FFFu + ((u >> 16) & 1u);   // round-to-nearest-even
  return (short)(u >> 16);
}

__device__ __forceinline__ bf8_t cvt8(const float4 a, const float4 b) {
  bf8_t f;
  f[0] = f2bf(a.x); f[1] = f2bf(a.y); f[2] = f2bf(a.z); f[3] = f2bf(a.w);
  f[4] = f2bf(b.x); f[5] = f2bf(b.y); f[6] = f2bf(b.z); f[7] = f2bf(b.w);
  return f;
}

__global__ __launch_bounds__(256)
void fa_varlen_kernel(const float* __restrict__ Q, const float* __restrict__ K,
                      const float* __restrict__ V, const int* __restrict__ cuq,
                      const int* __restrict__ cuk, float* __restrict__ O) {
  const int h  = blockIdx.y;
  const int b  = blockIdx.x >> 4;   // 16 = max_seqlen_q / QBLK(64)
  const int qt = blockIdx.x & 15;

  const int q0   = cuq[b];
  const int lenq = cuq[b + 1] - q0;
  if (qt * 64 >= lenq) return;
  const int k0   = cuk[b];
  const int lenk = cuk[b + 1] - k0;

  const int tid  = threadIdx.x;
  const int wave = tid >> 6;
  const int lane = tid & 63;
  const int lo   = lane & 15;
  const int gp   = lane >> 4;       // 0..3

  const int qrow_base = qt * 64 + wave * 16;   // this wave's 16 q-rows

  // ---- Q A-fragments (rows = qrow_base + lo, k-dim = d), 4 d-blocks of 32
  bf8_t qf[4];
  {
    const int qr  = qrow_base + lo;
    const int qg  = q0 + (qr < lenq ? qr : lenq - 1);
    const float* qp = Q + ((size_t)qg * H_ + h) * D_;
    #pragma unroll
    for (int db = 0; db < 4; ++db) {
      const float4 a = *reinterpret_cast<const float4*>(qp + db * 32 + gp * 8);
      const float4 c = *reinterpret_cast<const float4*>(qp + db * 32 + gp * 8 + 4);
      qf[db] = cvt8(a, c);
    }
  }

  f32x4 acc[8];
  #pragma unroll
  for (int i = 0; i < 8; ++i) acc[i] = f32x4{0.f, 0.f, 0.f, 0.f};
  float m_r[4] = {-1e30f, -1e30f, -1e30f, -1e30f};
  float l_r[4] = {0.f, 0.f, 0.f, 0.f};

  // per-wave P transpose buffer: 16 rows x 32 cols bf16, row stride 40 shorts (80B)
  __shared__ __align__(16) short plds[4][16 * 40];
  short* pw = plds[wave];

  const float pre = 0.08838834764831845f / CAPF;  // (1/sqrt(D)) / cap

  const int nkt = (lenk + 31) >> 5;
  for (int kt = 0; kt < nkt; ++kt) {
    const int kb = kt * 32;

    // ---- QK^T -> S (16q x 32keys) as two 16x16 C-frags
    f32x4 s0 = f32x4{0.f, 0.f, 0.f, 0.f};
    f32x4 s1 = f32x4{0.f, 0.f, 0.f, 0.f};
    {
      const int key0 = kb + lo;
      const int key1 = kb + 16 + lo;
      const float* kp0 = K + ((size_t)(k0 + (key0 < lenk ? key0 : lenk - 1)) * H_ + h) * D_;
      const float* kp1 = K + ((size_t)(k0 + (key1 < lenk ? key1 : lenk - 1)) * H_ + h) * D_;
      #pragma unroll
      for (int db = 0; db < 4; ++db) {
        const int d0 = db * 32 + gp * 8;
        const float4 a0 = *reinterpret_cast<const float4*>(kp0 + d0);
        const float4 c0 = *reinterpret_cast<const float4*>(kp0 + d0 + 4);
        s0 = __builtin_amdgcn_mfma_f32_16x16x32_bf16(qf[db], cvt8(a0, c0), s0, 0, 0, 0);
        const float4 a1 = *reinterpret_cast<const float4*>(kp1 + d0);
        const float4 c1 = *reinterpret_cast<const float4*>(kp1 + d0 + 4);
        s1 = __builtin_amdgcn_mfma_f32_16x16x32_bf16(qf[db], cvt8(a1, c1), s1, 0, 0, 0);
      }
    }

    // ---- softcap + mask (C layout: row = 4*gp + r, col = nt*16 + lo)
    float sv[8];
    #pragma unroll
    for (int nt = 0; nt < 2; ++nt) {
      const bool valid = (kb + nt * 16 + lo) < lenk;
      const f32x4 sc = nt ? s1 : s0;
      #pragma unroll
      for (int r = 0; r < 4; ++r) {
        float x = sc[r] * pre;
        x = fminf(fmaxf(x, -8.f), 8.f);
        const float e2 = __expf(2.f * x);
        const float t = CAPF * (1.f - 2.f / (e2 + 1.f));  // cap * tanh(x)
        sv[nt * 4 + r] = valid ? t : -1e9f;
      }
    }

    // ---- online softmax: row max over 16 cols (lanes within group)
    float tm[4];
    #pragma unroll
    for (int r = 0; r < 4; ++r) tm[r] = fmaxf(sv[r], sv[4 + r]);
    #pragma unroll
    for (int off = 1; off < 16; off <<= 1) {
      #pragma unroll
      for (int r = 0; r < 4; ++r) tm[r] = fmaxf(tm[r], __shfl_xor(tm[r], off, 16));
    }
    float corr[4];
    #pragma unroll
    for (int r = 0; r < 4; ++r) {
      const float mn = fmaxf(m_r[r], tm[r]);
      corr[r] = __expf(m_r[r] - mn);
      m_r[r] = mn;
    }
    float ps[4];
    #pragma unroll
    for (int r = 0; r < 4; ++r) {
      const float p0 = __expf(sv[r] - m_r[r]);
      const float p1 = __expf(sv[4 + r] - m_r[r]);
      sv[r] = p0; sv[4 + r] = p1;
      ps[r] = p0 + p1;
    }
    #pragma unroll
    for (int off = 1; off < 16; off <<= 1) {
      #pragma unroll
      for (int r = 0; r < 4; ++r) ps[r] += __shfl_xor(ps[r], off, 16);
    }
    #pragma unroll
    for (int r = 0; r < 4; ++r) l_r[r] = l_r[r] * corr[r] + ps[r];
    #pragma unroll
    for (int nt = 0; nt < 8; ++nt) {
      #pragma unroll
      for (int r = 0; r < 4; ++r) acc[nt][r] *= corr[r];
    }

    // ---- P: C-layout -> A-layout via LDS transpose (per-wave buffer)
    #pragma unroll
    for (int nt = 0; nt < 2; ++nt) {
      #pragma unroll
      for (int r = 0; r < 4; ++r)
        pw[(4 * gp + r) * 40 + nt * 16 + lo] = f2bf(sv[nt * 4 + r]);
    }
    asm volatile("s_waitcnt lgkmcnt(0)" ::: "memory");
    __builtin_amdgcn_sched_barrier(0);
    const bf8_t pf = *reinterpret_cast<const bf8_t*>(&pw[lo * 40 + gp * 8]);

    // ---- PV: O[16q x 128d] += P(16x32) * V(32x128)
    #pragma unroll
    for (int nt = 0; nt < 8; ++nt) {
      bf8_t vf;
      #pragma unroll
      for (int i = 0; i < 8; ++i) {
        int key = kb + gp * 8 + i;
        key = key < lenk ? key : lenk - 1;
        vf[i] = f2bf(V[((size_t)(k0 + key) * H_ + h) * D_ + nt * 16 + lo]);
      }
      acc[nt] = __builtin_amdgcn_mfma_f32_16x16x32_bf16(pf, vf, acc[nt], 0, 0, 0);
    }
  }

  // ---- epilogue: O = acc / l  (row = qrow_base + 4*gp + r, col = nt*16 + lo)
  #pragma unroll
  for (int r = 0; r < 4; ++r) {
    const int qr = qrow_base + 4 * gp + r;
    if (qr < lenq) {
      const float inv_l = 1.0f / l_r[r];
      float* op = O + ((size_t)(q0 + qr) * H_ + h) * D_;
      #pragma unroll
      for (int nt = 0; nt < 8; ++nt)
        op[nt * 16 + lo] = acc[nt][r] * inv_l;
    }
  }
}

extern "C" void kernel_launch(void* const* d_in, const int* in_sizes, int n_in,
                              void* d_out, int out_size, void* d_ws, size_t ws_size,
                              hipStream_t stream) {
  const float* Q  = (const float*)d_in[0];
  const float* K  = (const float*)d_in[1];
  const float* V  = (const float*)d_in[2];
  const int* cuq  = (const int*)d_in[3];
  const int* cuk  = (const int*)d_in[4];
  float* out      = (float*)d_out;
  const int B = in_sizes[3] - 1;          // 4 sequences
  dim3 grid(B * 16, H_);                  // 16 = max_seqlen_q(1024) / QBLK(64)
  fa_varlen_kernel<<<grid, 256, 0, stream>>>(Q, K, V, cuq, cuk, out);
}

// Round 3
// 191.221 us; speedup vs baseline: 1.5372x; 1.5372x over previous
//
#include <hip/hip_runtime.h>

#define H_ 16
#define D_ 128
#define CAPF 20.0f

typedef __attribute__((ext_vector_type(4))) float f32x4;
typedef __attribute__((ext_vector_type(8))) short bf8_t;  // 8 bf16 (4 VGPRs)

__device__ __forceinline__ short f2bf(float x) {
  unsigned u = __builtin_bit_cast(unsigned, x);
  u += 0x7FFFu + ((u >> 16) & 1u);   // RNE
  return (short)(u >> 16);
}

__device__ __forceinline__ bf8_t cvt8(const f32x4 a, const f32x4 b) {
  bf8_t f;
  f[0] = f2bf(a[0]); f[1] = f2bf(a[1]); f[2] = f2bf(a[2]); f[3] = f2bf(a[3]);
  f[4] = f2bf(b[0]); f[5] = f2bf(b[1]); f[6] = f2bf(b[2]); f[7] = f2bf(b[3]);
  return f;
}

__global__ __launch_bounds__(256)
void fa_varlen_kernel(const float* __restrict__ Q, const float* __restrict__ K,
                      const float* __restrict__ V, const int* __restrict__ cuq,
                      const int* __restrict__ cuk, float* __restrict__ O) {
  // K tile [64 key][128 d] bf16; 16B chunks XOR-swizzled:
  //   byte = key*256 + ((dchunk*16) ^ ((key&7)<<4))
  __shared__ __align__(16) short k_lds[64 * 128];
  // V tile TRANSPOSED [128 d][64 key], row stride 72 shorts (144 B)
  __shared__ __align__(16) short vt_lds[128 * 72];
  // P per wave [16 q][64 key], row stride 72 shorts
  __shared__ __align__(16) short p_lds[4][16 * 72];

  const int h  = blockIdx.y;
  const int b  = blockIdx.x >> 4;
  const int qt = blockIdx.x & 15;

  const int q0   = cuq[b];
  const int lenq = cuq[b + 1] - q0;
  if (qt * 64 >= lenq) return;
  const int k0   = cuk[b];
  const int lenk = cuk[b + 1] - k0;

  const int tid  = threadIdx.x;
  const int wave = tid >> 6;
  const int lane = tid & 63;
  const int lo   = lane & 15;
  const int gp   = lane >> 4;

  const int qrow_base = qt * 64 + wave * 16;

  // ---- Q A-fragments (row = lo, k = d), 4 d-blocks of 32
  bf8_t qf[4];
  {
    const int qr = qrow_base + lo;
    const int qg = q0 + (qr < lenq ? qr : lenq - 1);
    const float* qp = Q + ((size_t)qg * H_ + h) * D_;
    #pragma unroll
    for (int db = 0; db < 4; ++db) {
      const f32x4 a = *reinterpret_cast<const f32x4*>(qp + db * 32 + gp * 8);
      const f32x4 c = *reinterpret_cast<const f32x4*>(qp + db * 32 + gp * 8 + 4);
      qf[db] = cvt8(a, c);
    }
  }

  f32x4 acc[8];
  #pragma unroll
  for (int i = 0; i < 8; ++i) acc[i] = f32x4{0.f, 0.f, 0.f, 0.f};
  float m_r[4] = {-1e30f, -1e30f, -1e30f, -1e30f};
  float l_r[4] = {0.f, 0.f, 0.f, 0.f};

  char* kbase = (char*)k_lds;
  char* vtb   = (char*)vt_lds;
  short* pw   = p_lds[wave];

  // K staging ids: thread -> (key = tid>>4 (+16i), dchunk = tid&15)
  const int skey = tid >> 4;
  const int ssub = tid & 15;
  const float* Kb = K + h * D_ + ssub * 8;
  // V staging ids: thread -> (key octet = tid>>5, d quad = tid&31)
  const int vk8 = tid >> 5;
  const int vdq = tid & 31;
  const float* Vb = V + h * D_ + vdq * 4;

  const float pre = 0.08838834764831845f / CAPF;  // (1/sqrt(D)) / cap

  const int nkt = (lenk + 63) >> 6;
  for (int kt = 0; kt < nkt; ++kt) {
    const int kb = kt * 64;

    __syncthreads();   // previous tile fully consumed
    // ---- stage K (vectorized b128, XOR-swizzled)
    #pragma unroll
    for (int i = 0; i < 4; ++i) {
      const int key = skey + i * 16;
      const int kk = kb + key;
      const size_t gk = (size_t)(k0 + (kk < lenk ? kk : lenk - 1));
      const float* kp = Kb + gk * (H_ * D_);
      *(bf8_t*)(kbase + key * 256 + ((ssub * 16) ^ ((key & 7) << 4))) =
          cvt8(*(const f32x4*)kp, *(const f32x4*)(kp + 4));
    }
    // ---- stage V transposed via register transpose:
    // load 8 keys x 4 d (f32x4 each), write 4 x b128 (8 keys at one d)
    {
      f32x4 r0, r1, r2, r3, r4, r5, r6, r7;
      #pragma unroll
      for (int j = 0; j < 8; ++j) {
        const int kk = kb + vk8 * 8 + j;
        const size_t gk = (size_t)(k0 + (kk < lenk ? kk : lenk - 1));
        const f32x4 t = *(const f32x4*)(Vb + gk * (H_ * D_));
        if (j == 0) r0 = t; else if (j == 1) r1 = t; else if (j == 2) r2 = t;
        else if (j == 3) r3 = t; else if (j == 4) r4 = t; else if (j == 5) r5 = t;
        else if (j == 6) r6 = t; else r7 = t;
      }
      #pragma unroll
      for (int dd = 0; dd < 4; ++dd) {
        bf8_t w;
        w[0] = f2bf(r0[dd]); w[1] = f2bf(r1[dd]); w[2] = f2bf(r2[dd]);
        w[3] = f2bf(r3[dd]); w[4] = f2bf(r4[dd]); w[5] = f2bf(r5[dd]);
        w[6] = f2bf(r6[dd]); w[7] = f2bf(r7[dd]);
        // vt_lds[d][key8*8 .. +7], d = 4*vdq+dd
        *(bf8_t*)(vtb + (4 * vdq + dd) * 144 + vk8 * 16) = w;
      }
    }
    __syncthreads();

    // ---- QK^T: S (16q x 64k) as 4 C-frags
    f32x4 s[4];
    #pragma unroll
    for (int kq = 0; kq < 4; ++kq) s[kq] = f32x4{0.f, 0.f, 0.f, 0.f};
    #pragma unroll
    for (int db = 0; db < 4; ++db) {
      #pragma unroll
      for (int kq = 0; kq < 4; ++kq) {
        const bf8_t kf = *(const bf8_t*)(kbase + (kq * 16 + lo) * 256 +
                                         ((db * 64 + gp * 16) ^ ((lo & 7) << 4)));
        s[kq] = __builtin_amdgcn_mfma_f32_16x16x32_bf16(qf[db], kf, s[kq], 0, 0, 0);
      }
    }

    // ---- softcap + mask (C layout: row = 4*gp + r, col = kq*16 + lo)
    float sv[4][4];
    #pragma unroll
    for (int kq = 0; kq < 4; ++kq) {
      const bool valid = (kb + kq * 16 + lo) < lenk;
      #pragma unroll
      for (int r = 0; r < 4; ++r) {
        float x = s[kq][r] * pre;
        x = fminf(fmaxf(x, -8.f), 8.f);
        const float e2 = __expf(2.f * x);
        const float t = CAPF * (1.f - 2.f / (e2 + 1.f));
        sv[kq][r] = valid ? t : -1e9f;
      }
    }

    // ---- online softmax
    float tm[4];
    #pragma unroll
    for (int r = 0; r < 4; ++r)
      tm[r] = fmaxf(fmaxf(sv[0][r], sv[1][r]), fmaxf(sv[2][r], sv[3][r]));
    #pragma unroll
    for (int off = 1; off < 16; off <<= 1) {
      #pragma unroll
      for (int r = 0; r < 4; ++r) tm[r] = fmaxf(tm[r], __shfl_xor(tm[r], off, 16));
    }
    float corr[4];
    #pragma unroll
    for (int r = 0; r < 4; ++r) {
      const float mn = fmaxf(m_r[r], tm[r]);
      corr[r] = __expf(m_r[r] - mn);
      m_r[r] = mn;
    }
    float ps[4] = {0.f, 0.f, 0.f, 0.f};
    #pragma unroll
    for (int kq = 0; kq < 4; ++kq) {
      #pragma unroll
      for (int r = 0; r < 4; ++r) {
        const float p = __expf(sv[kq][r] - m_r[r]);
        sv[kq][r] = p;
        ps[r] += p;
      }
    }
    #pragma unroll
    for (int off = 1; off < 16; off <<= 1) {
      #pragma unroll
      for (int r = 0; r < 4; ++r) ps[r] += __shfl_xor(ps[r], off, 16);
    }
    #pragma unroll
    for (int r = 0; r < 4; ++r) l_r[r] = l_r[r] * corr[r] + ps[r];
    #pragma unroll
    for (int nt = 0; nt < 8; ++nt) {
      #pragma unroll
      for (int r = 0; r < 4; ++r) acc[nt][r] *= corr[r];
    }

    // ---- P write (plain layout: pw[q][key])
    #pragma unroll
    for (int kq = 0; kq < 4; ++kq) {
      #pragma unroll
      for (int r = 0; r < 4; ++r)
        pw[(4 * gp + r) * 72 + kq * 16 + lo] = f2bf(sv[kq][r]);
    }

    // ---- PV: O[16q x 128d] += P(16x64) * V(64x128), 2 k-steps of 32
    #pragma unroll
    for (int ks = 0; ks < 2; ++ks) {
      const bf8_t pf = *(const bf8_t*)(pw + lo * 72 + ks * 32 + gp * 8);
      #pragma unroll
      for (int nt = 0; nt < 8; ++nt) {
        // slot (gp,i): V[key = 32ks + 8gp + i][d = 16nt + lo]
        const bf8_t vf = *(const bf8_t*)(vtb + (nt * 16 + lo) * 144 + ks * 64 + gp * 16);
        acc[nt] = __builtin_amdgcn_mfma_f32_16x16x32_bf16(pf, vf, acc[nt], 0, 0, 0);
      }
    }
  }

  // ---- epilogue: O = acc / l  (row = qrow_base + 4*gp + r, col = nt*16 + lo)
  #pragma unroll
  for (int r = 0; r < 4; ++r) {
    const int qr = qrow_base + 4 * gp + r;
    if (qr < lenq) {
      const float inv_l = 1.0f / l_r[r];
      float* op = O + ((size_t)(q0 + qr) * H_ + h) * D_;
      #pragma unroll
      for (int nt = 0; nt < 8; ++nt)
        op[nt * 16 + lo] = acc[nt][r] * inv_l;
    }
  }
}

extern "C" void kernel_launch(void* const* d_in, const int* in_sizes, int n_in,
                              void* d_out, int out_size, void* d_ws, size_t ws_size,
                              hipStream_t stream) {
  const float* Q  = (const float*)d_in[0];
  const float* K  = (const float*)d_in[1];
  const float* V  = (const float*)d_in[2];
  const int* cuq  = (const int*)d_in[3];
  const int* cuk  = (const int*)d_in[4];
  float* out      = (float*)d_out;
  const int B = in_sizes[3] - 1;
  dim3 grid(B * 16, H_);
  fa_varlen_kernel<<<grid, 256, 0, stream>>>(Q, K, V, cuq, cuk, out);
}

// Round 4
// 137.095 us; speedup vs baseline: 2.1441x; 1.3948x over previous
//
#include <hip/hip_runtime.h>

#define H_ 16
#define D_ 128
#define CAPF 20.0f

typedef __attribute__((ext_vector_type(4))) float f32x4;
typedef __attribute__((ext_vector_type(8))) short bf8_t;  // 8 bf16 (4 VGPRs)

__device__ __forceinline__ short f2bf(float x) {
  unsigned u = __builtin_bit_cast(unsigned, x);
  u += 0x7FFFu + ((u >> 16) & 1u);   // RNE
  return (short)(u >> 16);
}

__device__ __forceinline__ bf8_t cvt8(const f32x4 a, const f32x4 b) {
  bf8_t f;
  f[0] = f2bf(a[0]); f[1] = f2bf(a[1]); f[2] = f2bf(a[2]); f[3] = f2bf(a[3]);
  f[4] = f2bf(b[0]); f[5] = f2bf(b[1]); f[6] = f2bf(b[2]); f[7] = f2bf(b[3]);
  return f;
}

__global__ __launch_bounds__(256, 2)
void fa_varlen_kernel(const float* __restrict__ Q, const float* __restrict__ K,
                      const float* __restrict__ V, const int* __restrict__ cuq,
                      const int* __restrict__ cuk, float* __restrict__ O) {
  // K tile [64 key][128 d] bf16; 16B chunks XOR-swizzled:
  //   byte = key*256 + ((dchunk*16) ^ ((key&7)<<4))
  __shared__ __align__(16) short k_lds[64 * 128];
  // V tile TRANSPOSED [128 d][64 key], row stride 72 shorts (144 B);
  // key-octet chunk XOR-swizzled by ((d>>2)&7): write-uniform + read-uniform
  __shared__ __align__(16) short vt_lds[128 * 72];
  // P per wave [16 q][64 key], row stride 72 shorts
  __shared__ __align__(16) short p_lds[4][16 * 72];

  const int h  = blockIdx.y;
  const int b  = blockIdx.x >> 4;
  const int qt = blockIdx.x & 15;

  const int q0   = cuq[b];
  const int lenq = cuq[b + 1] - q0;
  if (qt * 64 >= lenq) return;
  const int k0   = cuk[b];
  const int lenk = cuk[b + 1] - k0;

  const int tid  = threadIdx.x;
  const int wave = tid >> 6;
  const int lane = tid & 63;
  const int lo   = lane & 15;
  const int gp   = lane >> 4;

  const int qrow_base = qt * 64 + wave * 16;

  // ---- Q A-fragments (row = lo, k = d), 4 d-blocks of 32
  bf8_t qf[4];
  {
    const int qr = qrow_base + lo;
    const int qg = q0 + (qr < lenq ? qr : lenq - 1);
    const float* qp = Q + ((size_t)qg * H_ + h) * D_;
    #pragma unroll
    for (int db = 0; db < 4; ++db) {
      const f32x4 a = *reinterpret_cast<const f32x4*>(qp + db * 32 + gp * 8);
      const f32x4 c = *reinterpret_cast<const f32x4*>(qp + db * 32 + gp * 8 + 4);
      qf[db] = cvt8(a, c);
    }
  }

  f32x4 acc[8];
  #pragma unroll
  for (int i = 0; i < 8; ++i) acc[i] = f32x4{0.f, 0.f, 0.f, 0.f};
  float m_r[4] = {-1e30f, -1e30f, -1e30f, -1e30f};
  float l_r[4] = {0.f, 0.f, 0.f, 0.f};

  char* kbase = (char*)k_lds;
  char* vtb   = (char*)vt_lds;
  short* pw   = p_lds[wave];

  // K staging ids: thread -> (key = tid>>4 (+16i), dchunk = tid&15)
  const int skey = tid >> 4;
  const int ssub = tid & 15;
  const float* Kb = K + h * D_ + ssub * 8;
  // V staging ids: thread -> (key octet = tid>>5, d quad = tid&31)
  const int vk8 = tid >> 5;
  const int vdq = tid & 31;
  const float* Vb = V + h * D_ + vdq * 4;

  const float pre = 0.08838834764831845f / CAPF;  // (1/sqrt(D)) / cap

  // ---- async staging registers (tile t+1 in flight during compute on t)
  f32x4 kr[8];  // 4 keys x 32B
  f32x4 vr[8];  // 8 keys x 16B

  auto issue_loads = [&](int kb_next) {
    #pragma unroll
    for (int i = 0; i < 4; ++i) {
      const int kk = kb_next + skey + i * 16;
      const size_t gk = (size_t)(k0 + (kk < lenk ? kk : lenk - 1));
      const float* kp = Kb + gk * (H_ * D_);
      kr[2 * i]     = *(const f32x4*)kp;
      kr[2 * i + 1] = *(const f32x4*)(kp + 4);
    }
    #pragma unroll
    for (int j = 0; j < 8; ++j) {
      const int kk = kb_next + vk8 * 8 + j;
      const size_t gk = (size_t)(k0 + (kk < lenk ? kk : lenk - 1));
      vr[j] = *(const f32x4*)(Vb + gk * (H_ * D_));
    }
  };

  auto write_tile = [&]() {
    #pragma unroll
    for (int i = 0; i < 4; ++i) {
      const int key = skey + i * 16;
      *(bf8_t*)(kbase + key * 256 + ((ssub * 16) ^ ((key & 7) << 4))) =
          cvt8(kr[2 * i], kr[2 * i + 1]);
    }
    #pragma unroll
    for (int dd = 0; dd < 4; ++dd) {
      bf8_t w;
      #pragma unroll
      for (int j = 0; j < 8; ++j) w[j] = f2bf(vr[j][dd]);
      // row d = 4*vdq+dd; key-octet vk8 stored at chunk vk8 ^ ((d>>2)&7) = vk8 ^ (vdq&7)
      *(bf8_t*)(vtb + (4 * vdq + dd) * 144 + ((vk8 ^ (vdq & 7)) << 4)) = w;
    }
  };

  // ---- prologue: stage tile 0
  issue_loads(0);
  write_tile();
  __syncthreads();

  const int nkt = (lenk + 63) >> 6;
  for (int kt = 0; kt < nkt; ++kt) {
    const int kb = kt * 64;

    // issue next tile's global loads NOW; they drain under this tile's compute
    if (kt + 1 < nkt) issue_loads(kb + 64);
    __builtin_amdgcn_sched_barrier(0);  // pin loads before compute

    // ---- QK^T: S (16q x 64k) as 4 C-frags
    f32x4 s[4];
    #pragma unroll
    for (int kq = 0; kq < 4; ++kq) s[kq] = f32x4{0.f, 0.f, 0.f, 0.f};
    __builtin_amdgcn_s_setprio(1);
    #pragma unroll
    for (int db = 0; db < 4; ++db) {
      #pragma unroll
      for (int kq = 0; kq < 4; ++kq) {
        const bf8_t kf = *(const bf8_t*)(kbase + (kq * 16 + lo) * 256 +
                                         ((db * 64 + gp * 16) ^ ((lo & 7) << 4)));
        s[kq] = __builtin_amdgcn_mfma_f32_16x16x32_bf16(qf[db], kf, s[kq], 0, 0, 0);
      }
    }
    __builtin_amdgcn_s_setprio(0);

    // ---- softcap + mask (C layout: row = 4*gp + r, col = kq*16 + lo)
    float sv[4][4];
    #pragma unroll
    for (int kq = 0; kq < 4; ++kq) {
      const bool valid = (kb + kq * 16 + lo) < lenk;
      #pragma unroll
      for (int r = 0; r < 4; ++r) {
        float x = s[kq][r] * pre;
        x = fminf(fmaxf(x, -8.f), 8.f);
        const float e2 = __expf(2.f * x);
        const float t = CAPF * (1.f - 2.f / (e2 + 1.f));
        sv[kq][r] = valid ? t : -1e9f;
      }
    }

    // ---- online softmax
    float tm[4];
    #pragma unroll
    for (int r = 0; r < 4; ++r)
      tm[r] = fmaxf(fmaxf(sv[0][r], sv[1][r]), fmaxf(sv[2][r], sv[3][r]));
    #pragma unroll
    for (int off = 1; off < 16; off <<= 1) {
      #pragma unroll
      for (int r = 0; r < 4; ++r) tm[r] = fmaxf(tm[r], __shfl_xor(tm[r], off, 16));
    }
    float corr[4];
    #pragma unroll
    for (int r = 0; r < 4; ++r) {
      const float mn = fmaxf(m_r[r], tm[r]);
      corr[r] = __expf(m_r[r] - mn);
      m_r[r] = mn;
    }
    float ps[4] = {0.f, 0.f, 0.f, 0.f};
    #pragma unroll
    for (int kq = 0; kq < 4; ++kq) {
      #pragma unroll
      for (int r = 0; r < 4; ++r) {
        const float p = __expf(sv[kq][r] - m_r[r]);
        sv[kq][r] = p;
        ps[r] += p;
      }
    }
    #pragma unroll
    for (int off = 1; off < 16; off <<= 1) {
      #pragma unroll
      for (int r = 0; r < 4; ++r) ps[r] += __shfl_xor(ps[r], off, 16);
    }
    #pragma unroll
    for (int r = 0; r < 4; ++r) l_r[r] = l_r[r] * corr[r] + ps[r];
    #pragma unroll
    for (int nt = 0; nt < 8; ++nt) {
      #pragma unroll
      for (int r = 0; r < 4; ++r) acc[nt][r] *= corr[r];
    }

    // ---- P write (plain layout: pw[q][key])
    #pragma unroll
    for (int kq = 0; kq < 4; ++kq) {
      #pragma unroll
      for (int r = 0; r < 4; ++r)
        pw[(4 * gp + r) * 72 + kq * 16 + lo] = f2bf(sv[kq][r]);
    }

    // ---- PV: O[16q x 128d] += P(16x64) * V(64x128), 2 k-steps of 32
    __builtin_amdgcn_s_setprio(1);
    #pragma unroll
    for (int ks = 0; ks < 2; ++ks) {
      const bf8_t pf = *(const bf8_t*)(pw + lo * 72 + ks * 32 + gp * 8);
      #pragma unroll
      for (int nt = 0; nt < 8; ++nt) {
        // slot (gp,i): V[key = 32ks + 8gp + i][d = 16nt + lo]
        const int d = nt * 16 + lo;
        const bf8_t vf = *(const bf8_t*)(
            vtb + d * 144 + (((4 * ks + gp) ^ ((4 * nt + (lo >> 2)) & 7)) << 4));
        acc[nt] = __builtin_amdgcn_mfma_f32_16x16x32_bf16(pf, vf, acc[nt], 0, 0, 0);
      }
    }
    __builtin_amdgcn_s_setprio(0);

    __syncthreads();                       // all waves done reading tile kt
    if (kt + 1 < nkt) write_tile();        // land tile kt+1 (waits vmcnt inside)
    __syncthreads();                       // tile kt+1 visible
  }

  // ---- epilogue: O = acc / l  (row = qrow_base + 4*gp + r, col = nt*16 + lo)
  #pragma unroll
  for (int r = 0; r < 4; ++r) {
    const int qr = qrow_base + 4 * gp + r;
    if (qr < lenq) {
      const float inv_l = 1.0f / l_r[r];
      float* op = O + ((size_t)(q0 + qr) * H_ + h) * D_;
      #pragma unroll
      for (int nt = 0; nt < 8; ++nt)
        op[nt * 16 + lo] = acc[nt][r] * inv_l;
    }
  }
}

extern "C" void kernel_launch(void* const* d_in, const int* in_sizes, int n_in,
                              void* d_out, int out_size, void* d_ws, size_t ws_size,
                              hipStream_t stream) {
  const float* Q  = (const float*)d_in[0];
  const float* K  = (const float*)d_in[1];
  const float* V  = (const float*)d_in[2];
  const int* cuq  = (const int*)d_in[3];
  const int* cuk  = (const int*)d_in[4];
  float* out      = (float*)d_out;
  const int B = in_sizes[3] - 1;
  dim3 grid(B * 16, H_);
  fa_varlen_kernel<<<grid, 256, 0, stream>>>(Q, K, V, cuq, cuk, out);
}

// Round 6
// 95.406 us; speedup vs baseline: 3.0810x; 1.4370x over previous
//
#include <hip/hip_runtime.h>

#define H_ 16
#define D_ 128
#define CAPF 20.0f

typedef __attribute__((ext_vector_type(4))) float f32x4;
typedef __attribute__((ext_vector_type(8))) short bf8_t;   // 8 bf16 (4 VGPRs)
typedef __attribute__((ext_vector_type(4))) unsigned int u32x4;

__device__ __forceinline__ short f2bf(float x) {
  unsigned u = __builtin_bit_cast(unsigned, x);
  u += 0x7FFFu + ((u >> 16) & 1u);   // RNE
  return (short)(u >> 16);
}

__device__ __forceinline__ unsigned cvt_pk(float a, float b) {
  unsigned r;
  asm("v_cvt_pk_bf16_f32 %0, %1, %2" : "=v"(r) : "v"(a), "v"(b));
  return r;  // low 16 = bf16(a), high 16 = bf16(b)
}

__device__ __forceinline__ bf8_t cvt8(const f32x4 a, const f32x4 b) {
  u32x4 r;
  r[0] = cvt_pk(a[0], a[1]); r[1] = cvt_pk(a[2], a[3]);
  r[2] = cvt_pk(b[0], b[1]); r[3] = cvt_pk(b[2], b[3]);
  return __builtin_bit_cast(bf8_t, r);
}

__global__ __launch_bounds__(256, 2)
void fa_varlen_kernel(const float* __restrict__ Q, const float* __restrict__ K,
                      const float* __restrict__ V, const int* __restrict__ cuq,
                      const int* __restrict__ cuk, float* __restrict__ O) {
  // K tile [64 key][128 d] bf16; 16B chunks XOR-swizzled by (key&7)
  __shared__ __align__(16) short k_lds[64 * 128];
  // V tile TRANSPOSED [128 d][64 key], row stride 72 shorts (144 B);
  // key-octet chunk XOR-swizzled by ((d>>3)&7): write- AND read-uniform (8 lanes/bank-group)
  __shared__ __align__(16) short vt_lds[128 * 72];
  // P per wave [16 q][64 key], row stride 72 shorts
  __shared__ __align__(16) short p_lds[4][16 * 72];

  const int h  = blockIdx.y;
  const int b  = blockIdx.x >> 4;
  const int qt = blockIdx.x & 15;

  const int q0   = cuq[b];
  const int lenq = cuq[b + 1] - q0;
  if (qt * 64 >= lenq) return;
  const int k0   = cuk[b];
  const int lenk = cuk[b + 1] - k0;

  const int tid  = threadIdx.x;
  const int wave = tid >> 6;
  const int lane = tid & 63;
  const int lo   = lane & 15;
  const int gp   = lane >> 4;

  const int qrow_base = qt * 64 + wave * 16;

  // ---- Q A-fragments (row = lo, k = d), 4 d-blocks of 32
  bf8_t qf[4];
  {
    const int qr = qrow_base + lo;
    const int qg = q0 + (qr < lenq ? qr : lenq - 1);
    const float* qp = Q + ((size_t)qg * H_ + h) * D_;
    #pragma unroll
    for (int db = 0; db < 4; ++db) {
      const f32x4 a = *reinterpret_cast<const f32x4*>(qp + db * 32 + gp * 8);
      const f32x4 c = *reinterpret_cast<const f32x4*>(qp + db * 32 + gp * 8 + 4);
      qf[db] = cvt8(a, c);
    }
  }

  f32x4 acc[8];
  #pragma unroll
  for (int i = 0; i < 8; ++i) acc[i] = f32x4{0.f, 0.f, 0.f, 0.f};
  float lp[4] = {0.f, 0.f, 0.f, 0.f};   // per-lane partial softmax denominator

  char* kbase = (char*)k_lds;
  char* vtb   = (char*)vt_lds;
  short* pw   = p_lds[wave];

  // K staging ids: thread -> (key = tid>>4 (+16i), dchunk = tid&15)
  const int skey = tid >> 4;
  const int ssub = tid & 15;
  const float* Kb = K + h * D_ + ssub * 8;
  // V staging ids: thread -> (key octet = tid>>5, d quad = tid&31)
  const int vk8 = tid >> 5;
  const int vdq = tid & 31;
  const float* Vb = V + h * D_ + vdq * 4;

  // p = exp(cap*tanh(S*scale/cap) - cap) = exp(-2cap / (exp(S*2*scale/cap)+1))
  const float c2n = 0.008838834764831845f;  // 2*(1/sqrt(128))/CAPF

  // ---- async staging registers (tile t+1 in flight during compute on t)
  f32x4 kr[8];
  f32x4 vr[8];

  auto issue_loads = [&](int kb_next) {
    #pragma unroll
    for (int i = 0; i < 4; ++i) {
      const int kk = kb_next + skey + i * 16;
      const size_t gk = (size_t)(k0 + (kk < lenk ? kk : lenk - 1));
      const float* kp = Kb + gk * (H_ * D_);
      kr[2 * i]     = *(const f32x4*)kp;
      kr[2 * i + 1] = *(const f32x4*)(kp + 4);
    }
    #pragma unroll
    for (int j = 0; j < 8; ++j) {
      const int kk = kb_next + vk8 * 8 + j;
      const size_t gk = (size_t)(k0 + (kk < lenk ? kk : lenk - 1));
      vr[j] = *(const f32x4*)(Vb + gk * (H_ * D_));
    }
  };

  auto write_tile = [&]() {
    #pragma unroll
    for (int i = 0; i < 4; ++i) {
      const int key = skey + i * 16;
      *(bf8_t*)(kbase + key * 256 + ((ssub * 16) ^ ((key & 7) << 4))) =
          cvt8(kr[2 * i], kr[2 * i + 1]);
    }
    #pragma unroll
    for (int dd = 0; dd < 4; ++dd) {
      u32x4 w;
      w[0] = cvt_pk(vr[0][dd], vr[1][dd]);
      w[1] = cvt_pk(vr[2][dd], vr[3][dd]);
      w[2] = cvt_pk(vr[4][dd], vr[5][dd]);
      w[3] = cvt_pk(vr[6][dd], vr[7][dd]);
      // row d = 4*vdq+dd; chunk vk8 at slot vk8 ^ ((d>>3)&7) = vk8 ^ ((vdq>>1)&7)
      *(u32x4*)(vtb + (4 * vdq + dd) * 144 + ((vk8 ^ ((vdq >> 1) & 7)) << 4)) = w;
    }
  };

  // ---- prologue: stage tile 0
  issue_loads(0);
  write_tile();
  __syncthreads();

  const int nkt = (lenk + 63) >> 6;
  for (int kt = 0; kt < nkt; ++kt) {
    const int kb = kt * 64;

    // issue next tile's global loads NOW; drain under this tile's compute
    if (kt + 1 < nkt) issue_loads(kb + 64);
    __builtin_amdgcn_sched_barrier(0);

    // ---- QK^T: S (16q x 64k) as 4 C-frags
    f32x4 s[4];
    #pragma unroll
    for (int kq = 0; kq < 4; ++kq) s[kq] = f32x4{0.f, 0.f, 0.f, 0.f};
    __builtin_amdgcn_s_setprio(1);
    #pragma unroll
    for (int db = 0; db < 4; ++db) {
      #pragma unroll
      for (int kq = 0; kq < 4; ++kq) {
        const bf8_t kf = *(const bf8_t*)(kbase + (kq * 16 + lo) * 256 +
                                         ((db * 64 + gp * 16) ^ ((lo & 7) << 4)));
        s[kq] = __builtin_amdgcn_mfma_f32_16x16x32_bf16(qf[db], kf, s[kq], 0, 0, 0);
      }
    }
    __builtin_amdgcn_s_setprio(0);

    // ---- fused softcap + exp(.-20), fixed max (capped scores bounded by +-20):
    //   p = exp(-40 * rcp(exp(S*c2n) + 1));  inf/0 propagate correctly, no clamp
    #pragma unroll
    for (int kq = 0; kq < 4; ++kq) {
      const bool valid = (kb + kq * 16 + lo) < lenk;
      #pragma unroll
      for (int r = 0; r < 4; ++r) {
        const float e2 = __expf(s[kq][r] * c2n);
        float p = __expf(-40.0f * __builtin_amdgcn_rcpf(e2 + 1.0f));
        p = valid ? p : 0.0f;
        lp[r] += p;
        pw[(4 * gp + r) * 72 + kq * 16 + lo] = f2bf(p);
      }
    }

    // ---- PV: O[16q x 128d] += P(16x64) * V(64x128), 2 k-steps of 32
    __builtin_amdgcn_s_setprio(1);
    #pragma unroll
    for (int ks = 0; ks < 2; ++ks) {
      const bf8_t pf = *(const bf8_t*)(pw + lo * 72 + ks * 32 + gp * 8);
      #pragma unroll
      for (int nt = 0; nt < 8; ++nt) {
        // slot (gp,i): V[key = 32ks + 8gp + i][d = 16nt + lo]
        const int d = nt * 16 + lo;
        const bf8_t vf = *(const bf8_t*)(
            vtb + d * 144 + (((4 * ks + gp) ^ ((2 * nt + (lo >> 3)) & 7)) << 4));
        acc[nt] = __builtin_amdgcn_mfma_f32_16x16x32_bf16(pf, vf, acc[nt], 0, 0, 0);
      }
    }
    __builtin_amdgcn_s_setprio(0);

    __syncthreads();                       // all waves done reading tile kt
    if (kt + 1 < nkt) write_tile();        // land tile kt+1
    __syncthreads();                       // tile kt+1 visible
  }

  // ---- epilogue: reduce l across the 16 lanes of each group, then O = acc/l
  #pragma unroll
  for (int off = 1; off < 16; off <<= 1) {
    #pragma unroll
    for (int r = 0; r < 4; ++r) lp[r] += __shfl_xor(lp[r], off, 16);
  }
  #pragma unroll
  for (int r = 0; r < 4; ++r) {
    const int qr = qrow_base + 4 * gp + r;
    if (qr < lenq) {
      const float inv_l = 1.0f / lp[r];
      float* op = O + ((size_t)(q0 + qr) * H_ + h) * D_;
      #pragma unroll
      for (int nt = 0; nt < 8; ++nt)
        op[nt * 16 + lo] = acc[nt][r] * inv_l;
    }
  }
}

extern "C" void kernel_launch(void* const* d_in, const int* in_sizes, int n_in,
                              void* d_out, int out_size, void* d_ws, size_t ws_size,
                              hipStream_t stream) {
  const float* Q  = (const float*)d_in[0];
  const float* K  = (const float*)d_in[1];
  const float* V  = (const float*)d_in[2];
  const int* cuq  = (const int*)d_in[3];
  const int* cuk  = (const int*)d_in[4];
  float* out      = (float*)d_out;
  const int B = in_sizes[3] - 1;
  dim3 grid(B * 16, H_);
  fa_varlen_kernel<<<grid, 256, 0, stream>>>(Q, K, V, cuq, cuk, out);
}

// Round 7
// 92.687 us; speedup vs baseline: 3.1714x; 1.0293x over previous
//
#include <hip/hip_runtime.h>

#define H_ 16
#define D_ 128
#define CAPF 20.0f

typedef __attribute__((ext_vector_type(4))) float f32x4;
typedef __attribute__((ext_vector_type(8))) short bf8_t;   // 8 bf16 (4 VGPRs)
typedef __attribute__((ext_vector_type(4))) unsigned int u32x4;

__device__ __forceinline__ short f2bf(float x) {
  unsigned u = __builtin_bit_cast(unsigned, x);
  u += 0x7FFFu + ((u >> 16) & 1u);   // RNE
  return (short)(u >> 16);
}

__device__ __forceinline__ unsigned cvt_pk(float a, float b) {
  unsigned r;
  asm("v_cvt_pk_bf16_f32 %0, %1, %2" : "=v"(r) : "v"(a), "v"(b));
  return r;  // low 16 = bf16(a), high 16 = bf16(b)
}

__device__ __forceinline__ bf8_t cvt8(const f32x4 a, const f32x4 b) {
  u32x4 r;
  r[0] = cvt_pk(a[0], a[1]); r[1] = cvt_pk(a[2], a[3]);
  r[2] = cvt_pk(b[0], b[1]); r[3] = cvt_pk(b[2], b[3]);
  return __builtin_bit_cast(bf8_t, r);
}

__global__ __launch_bounds__(256, 2)
void fa_varlen_kernel(const float* __restrict__ Q, const float* __restrict__ K,
                      const float* __restrict__ V, const int* __restrict__ cuq,
                      const int* __restrict__ cuk, float* __restrict__ O) {
  // DOUBLE-BUFFERED tiles:
  // K tile [64 key][128 d] bf16; 16B chunks XOR-swizzled by (key&7)
  __shared__ __align__(16) short k_lds[2][64 * 128];
  // V tile TRANSPOSED [128 d][64 key], row stride 72 shorts (144 B);
  // key-octet chunk XOR-swizzled by ((d>>3)&7): write- AND read-uniform
  __shared__ __align__(16) short vt_lds[2][128 * 72];
  // P per wave [16 q][64 key], row stride 72 shorts (wave-private, no dbuf needed)
  __shared__ __align__(16) short p_lds[4][16 * 72];

  const int h  = blockIdx.y;
  const int b  = blockIdx.x >> 4;
  const int qt = blockIdx.x & 15;

  const int q0   = cuq[b];
  const int lenq = cuq[b + 1] - q0;
  if (qt * 64 >= lenq) return;
  const int k0   = cuk[b];
  const int lenk = cuk[b + 1] - k0;

  const int tid  = threadIdx.x;
  const int wave = tid >> 6;
  const int lane = tid & 63;
  const int lo   = lane & 15;
  const int gp   = lane >> 4;

  const int qrow_base = qt * 64 + wave * 16;

  // ---- Q A-fragments (row = lo, k = d), 4 d-blocks of 32
  bf8_t qf[4];
  {
    const int qr = qrow_base + lo;
    const int qg = q0 + (qr < lenq ? qr : lenq - 1);
    const float* qp = Q + ((size_t)qg * H_ + h) * D_;
    #pragma unroll
    for (int db = 0; db < 4; ++db) {
      const f32x4 a = *reinterpret_cast<const f32x4*>(qp + db * 32 + gp * 8);
      const f32x4 c = *reinterpret_cast<const f32x4*>(qp + db * 32 + gp * 8 + 4);
      qf[db] = cvt8(a, c);
    }
  }

  f32x4 acc[8];
  #pragma unroll
  for (int i = 0; i < 8; ++i) acc[i] = f32x4{0.f, 0.f, 0.f, 0.f};
  float lp[4] = {0.f, 0.f, 0.f, 0.f};   // per-lane partial softmax denominator

  short* pw = p_lds[wave];

  // K staging ids: thread -> (key = tid>>4 (+16i), dchunk = tid&15)
  const int skey = tid >> 4;
  const int ssub = tid & 15;
  const float* Kb = K + h * D_ + ssub * 8;
  // V staging ids: thread -> (key octet = tid>>5, d quad = tid&31)
  const int vk8 = tid >> 5;
  const int vdq = tid & 31;
  const float* Vb = V + h * D_ + vdq * 4;

  // p = exp(cap*tanh(S*scale/cap) - cap) = exp(-2cap / (exp(S*2*scale/cap)+1))
  const float c2n = 0.008838834764831845f;  // 2*(1/sqrt(128))/CAPF

  // ---- async staging registers (tile t+1 in flight during compute on t)
  f32x4 kr[8];
  f32x4 vr[8];

  auto issue_loads = [&](int kb_next) {
    #pragma unroll
    for (int i = 0; i < 4; ++i) {
      const int kk = kb_next + skey + i * 16;
      const size_t gk = (size_t)(k0 + (kk < lenk ? kk : lenk - 1));
      const float* kp = Kb + gk * (H_ * D_);
      kr[2 * i]     = *(const f32x4*)kp;
      kr[2 * i + 1] = *(const f32x4*)(kp + 4);
    }
    #pragma unroll
    for (int j = 0; j < 8; ++j) {
      const int kk = kb_next + vk8 * 8 + j;
      const size_t gk = (size_t)(k0 + (kk < lenk ? kk : lenk - 1));
      vr[j] = *(const f32x4*)(Vb + gk * (H_ * D_));
    }
  };

  auto write_tile = [&](int buf) {
    char* kb = (char*)k_lds[buf];
    char* vb = (char*)vt_lds[buf];
    #pragma unroll
    for (int i = 0; i < 4; ++i) {
      const int key = skey + i * 16;
      *(bf8_t*)(kb + key * 256 + ((ssub * 16) ^ ((key & 7) << 4))) =
          cvt8(kr[2 * i], kr[2 * i + 1]);
    }
    #pragma unroll
    for (int dd = 0; dd < 4; ++dd) {
      u32x4 w;
      w[0] = cvt_pk(vr[0][dd], vr[1][dd]);
      w[1] = cvt_pk(vr[2][dd], vr[3][dd]);
      w[2] = cvt_pk(vr[4][dd], vr[5][dd]);
      w[3] = cvt_pk(vr[6][dd], vr[7][dd]);
      // row d = 4*vdq+dd; chunk vk8 at slot vk8 ^ ((d>>3)&7) = vk8 ^ ((vdq>>1)&7)
      *(u32x4*)(vb + (4 * vdq + dd) * 144 + ((vk8 ^ ((vdq >> 1) & 7)) << 4)) = w;
    }
  };

  // ---- prologue: stage tile 0 into buffer 0
  issue_loads(0);
  write_tile(0);
  __syncthreads();

  const int nkt = (lenk + 63) >> 6;
  for (int kt = 0; kt < nkt; ++kt) {
    const int kb = kt * 64;
    char* kbase = (char*)k_lds[kt & 1];
    char* vtb   = (char*)vt_lds[kt & 1];

    // issue next tile's global loads NOW; drain under this tile's compute
    if (kt + 1 < nkt) issue_loads(kb + 64);
    __builtin_amdgcn_sched_barrier(0);

    // ---- QK^T: S (16q x 64k) as 4 C-frags
    f32x4 s[4];
    #pragma unroll
    for (int kq = 0; kq < 4; ++kq) s[kq] = f32x4{0.f, 0.f, 0.f, 0.f};
    __builtin_amdgcn_s_setprio(1);
    #pragma unroll
    for (int db = 0; db < 4; ++db) {
      #pragma unroll
      for (int kq = 0; kq < 4; ++kq) {
        const bf8_t kf = *(const bf8_t*)(kbase + (kq * 16 + lo) * 256 +
                                         ((db * 64 + gp * 16) ^ ((lo & 7) << 4)));
        s[kq] = __builtin_amdgcn_mfma_f32_16x16x32_bf16(qf[db], kf, s[kq], 0, 0, 0);
      }
    }
    __builtin_amdgcn_s_setprio(0);

    // ---- fused softcap + exp(.-20), fixed max (capped scores bounded by +-20):
    //   p = exp(-40 * rcp(exp(S*c2n) + 1));  inf/0 propagate correctly, no clamp
    #pragma unroll
    for (int kq = 0; kq < 4; ++kq) {
      const bool valid = (kb + kq * 16 + lo) < lenk;
      #pragma unroll
      for (int r = 0; r < 4; ++r) {
        const float e2 = __expf(s[kq][r] * c2n);
        float p = __expf(-40.0f * __builtin_amdgcn_rcpf(e2 + 1.0f));
        p = valid ? p : 0.0f;
        lp[r] += p;
        pw[(4 * gp + r) * 72 + kq * 16 + lo] = f2bf(p);
      }
    }

    // ---- PV: O[16q x 128d] += P(16x64) * V(64x128), 2 k-steps of 32
    __builtin_amdgcn_s_setprio(1);
    #pragma unroll
    for (int ks = 0; ks < 2; ++ks) {
      const bf8_t pf = *(const bf8_t*)(pw + lo * 72 + ks * 32 + gp * 8);
      #pragma unroll
      for (int nt = 0; nt < 8; ++nt) {
        // slot (gp,i): V[key = 32ks + 8gp + i][d = 16nt + lo]
        const int d = nt * 16 + lo;
        const bf8_t vf = *(const bf8_t*)(
            vtb + d * 144 + (((4 * ks + gp) ^ ((2 * nt + (lo >> 3)) & 7)) << 4));
        acc[nt] = __builtin_amdgcn_mfma_f32_16x16x32_bf16(pf, vf, acc[nt], 0, 0, 0);
      }
    }
    __builtin_amdgcn_s_setprio(0);

    // land tile kt+1 into the OTHER buffer (no barrier needed before the write:
    // every wave passed the end-of-(kt-1) barrier, so no one still reads it)
    if (kt + 1 < nkt) write_tile((kt + 1) & 1);
    __syncthreads();   // tile kt+1 visible; all waves done with buf[kt&1]
  }

  // ---- epilogue: reduce l across the 16 lanes of each group, then O = acc/l
  #pragma unroll
  for (int off = 1; off < 16; off <<= 1) {
    #pragma unroll
    for (int r = 0; r < 4; ++r) lp[r] += __shfl_xor(lp[r], off, 16);
  }
  #pragma unroll
  for (int r = 0; r < 4; ++r) {
    const int qr = qrow_base + 4 * gp + r;
    if (qr < lenq) {
      const float inv_l = 1.0f / lp[r];
      float* op = O + ((size_t)(q0 + qr) * H_ + h) * D_;
      #pragma unroll
      for (int nt = 0; nt < 8; ++nt)
        op[nt * 16 + lo] = acc[nt][r] * inv_l;
    }
  }
}

extern "C" void kernel_launch(void* const* d_in, const int* in_sizes, int n_in,
                              void* d_out, int out_size, void* d_ws, size_t ws_size,
                              hipStream_t stream) {
  const float* Q  = (const float*)d_in[0];
  const float* K  = (const float*)d_in[1];
  const float* V  = (const float*)d_in[2];
  const int* cuq  = (const int*)d_in[3];
  const int* cuk  = (const int*)d_in[4];
  float* out      = (float*)d_out;
  const int B = in_sizes[3] - 1;
  dim3 grid(B * 16, H_);
  fa_varlen_kernel<<<grid, 256, 0, stream>>>(Q, K, V, cuq, cuk, out);
}

// Round 8
// 91.514 us; speedup vs baseline: 3.2121x; 1.0128x over previous
//
#include <hip/hip_runtime.h>

#define H_ 16
#define D_ 128
#define CAPF 20.0f

typedef __attribute__((ext_vector_type(4))) float f32x4;
typedef __attribute__((ext_vector_type(8))) short bf8_t;   // 8 bf16 (4 VGPRs)
typedef __attribute__((ext_vector_type(4))) unsigned int u32x4;

__device__ __forceinline__ short f2bf(float x) {
  unsigned u = __builtin_bit_cast(unsigned, x);
  u += 0x7FFFu + ((u >> 16) & 1u);   // RNE
  return (short)(u >> 16);
}

__device__ __forceinline__ unsigned cvt_pk(float a, float b) {
  unsigned r;
  asm("v_cvt_pk_bf16_f32 %0, %1, %2" : "=v"(r) : "v"(a), "v"(b));
  return r;  // low 16 = bf16(a), high 16 = bf16(b)
}

__device__ __forceinline__ bf8_t cvt8(const f32x4 a, const f32x4 b) {
  u32x4 r;
  r[0] = cvt_pk(a[0], a[1]); r[1] = cvt_pk(a[2], a[3]);
  r[2] = cvt_pk(b[0], b[1]); r[3] = cvt_pk(b[2], b[3]);
  return __builtin_bit_cast(bf8_t, r);
}

__global__ __launch_bounds__(256, 2)
void fa_varlen_kernel(const float* __restrict__ Q, const float* __restrict__ K,
                      const float* __restrict__ V, const int* __restrict__ cuq,
                      const int* __restrict__ cuk, float* __restrict__ O) {
  // DOUBLE-BUFFERED K/V tiles (identical layouts to R7):
  __shared__ __align__(16) short k_lds[2][64 * 128];   // 32 KB
  __shared__ __align__(16) short vt_lds[2][128 * 72];  // 36.9 KB
  // P per wave [16 q][64 key], stride 72 shorts; reused across the 2 q-sets
  __shared__ __align__(16) short p_lds[4][16 * 72];    // 9.2 KB

  const int h  = blockIdx.y;
  const int b  = blockIdx.x >> 3;   // 8 = 1024 / QBLK(128)
  const int qt = blockIdx.x & 7;

  const int q0   = cuq[b];
  const int lenq = cuq[b + 1] - q0;
  if (qt * 128 >= lenq) return;
  const int k0   = cuk[b];
  const int lenk = cuk[b + 1] - k0;

  const int tid  = threadIdx.x;
  const int wave = tid >> 6;
  const int lane = tid & 63;
  const int lo   = lane & 15;
  const int gp   = lane >> 4;

  const int qrow_base = qt * 128 + wave * 32;   // this wave's 32 q-rows (2 sets of 16)

  // ---- Q A-fragments for both q-sets (row = lo, k = d), 4 d-blocks of 32
  bf8_t qf[2][4];
  #pragma unroll
  for (int s2 = 0; s2 < 2; ++s2) {
    const int qr = qrow_base + s2 * 16 + lo;
    const int qg = q0 + (qr < lenq ? qr : lenq - 1);
    const float* qp = Q + ((size_t)qg * H_ + h) * D_;
    #pragma unroll
    for (int db = 0; db < 4; ++db) {
      const f32x4 a = *reinterpret_cast<const f32x4*>(qp + db * 32 + gp * 8);
      const f32x4 c = *reinterpret_cast<const f32x4*>(qp + db * 32 + gp * 8 + 4);
      qf[s2][db] = cvt8(a, c);
    }
  }

  f32x4 acc[2][8];
  #pragma unroll
  for (int s2 = 0; s2 < 2; ++s2)
    #pragma unroll
    for (int i = 0; i < 8; ++i) acc[s2][i] = f32x4{0.f, 0.f, 0.f, 0.f};
  float lp[2][4] = {{0.f, 0.f, 0.f, 0.f}, {0.f, 0.f, 0.f, 0.f}};

  short* pw = p_lds[wave];

  // K staging ids: thread -> (key = tid>>4 (+16i), dchunk = tid&15)
  const int skey = tid >> 4;
  const int ssub = tid & 15;
  const float* Kb = K + h * D_ + ssub * 8;
  // V staging ids: thread -> (key octet = tid>>5, d quad = tid&31)
  const int vk8 = tid >> 5;
  const int vdq = tid & 31;
  const float* Vb = V + h * D_ + vdq * 4;

  const float c2n = 0.008838834764831845f;  // 2*(1/sqrt(128))/CAPF

  // ---- async staging registers (tile t+1 in flight during compute on t)
  f32x4 kr[8];
  f32x4 vr[8];

  auto issue_loads = [&](int kb_next) {
    #pragma unroll
    for (int i = 0; i < 4; ++i) {
      const int kk = kb_next + skey + i * 16;
      const size_t gk = (size_t)(k0 + (kk < lenk ? kk : lenk - 1));
      const float* kp = Kb + gk * (H_ * D_);
      kr[2 * i]     = *(const f32x4*)kp;
      kr[2 * i + 1] = *(const f32x4*)(kp + 4);
    }
    #pragma unroll
    for (int j = 0; j < 8; ++j) {
      const int kk = kb_next + vk8 * 8 + j;
      const size_t gk = (size_t)(k0 + (kk < lenk ? kk : lenk - 1));
      vr[j] = *(const f32x4*)(Vb + gk * (H_ * D_));
    }
  };

  auto write_tile = [&](int buf) {
    char* kb = (char*)k_lds[buf];
    char* vb = (char*)vt_lds[buf];
    #pragma unroll
    for (int i = 0; i < 4; ++i) {
      const int key = skey + i * 16;
      *(bf8_t*)(kb + key * 256 + ((ssub * 16) ^ ((key & 7) << 4))) =
          cvt8(kr[2 * i], kr[2 * i + 1]);
    }
    #pragma unroll
    for (int dd = 0; dd < 4; ++dd) {
      u32x4 w;
      w[0] = cvt_pk(vr[0][dd], vr[1][dd]);
      w[1] = cvt_pk(vr[2][dd], vr[3][dd]);
      w[2] = cvt_pk(vr[4][dd], vr[5][dd]);
      w[3] = cvt_pk(vr[6][dd], vr[7][dd]);
      *(u32x4*)(vb + (4 * vdq + dd) * 144 + ((vk8 ^ ((vdq >> 1) & 7)) << 4)) = w;
    }
  };

  // ---- prologue: stage tile 0 into buffer 0
  issue_loads(0);
  write_tile(0);
  __syncthreads();

  const int nkt = (lenk + 63) >> 6;
  for (int kt = 0; kt < nkt; ++kt) {
    const int kb = kt * 64;
    char* kbase = (char*)k_lds[kt & 1];
    char* vtb   = (char*)vt_lds[kt & 1];

    // issue next tile's global loads NOW; drain under this tile's compute
    if (kt + 1 < nkt) issue_loads(kb + 64);
    __builtin_amdgcn_sched_barrier(0);

    // ---- QK^T: S (32q x 64k) as 2 sets x 4 C-frags; each kf read feeds 2 MFMAs
    f32x4 s[2][4];
    #pragma unroll
    for (int s2 = 0; s2 < 2; ++s2)
      #pragma unroll
      for (int kq = 0; kq < 4; ++kq) s[s2][kq] = f32x4{0.f, 0.f, 0.f, 0.f};
    __builtin_amdgcn_s_setprio(1);
    #pragma unroll
    for (int db = 0; db < 4; ++db) {
      #pragma unroll
      for (int kq = 0; kq < 4; ++kq) {
        const bf8_t kf = *(const bf8_t*)(kbase + (kq * 16 + lo) * 256 +
                                         ((db * 64 + gp * 16) ^ ((lo & 7) << 4)));
        s[0][kq] = __builtin_amdgcn_mfma_f32_16x16x32_bf16(qf[0][db], kf, s[0][kq], 0, 0, 0);
        s[1][kq] = __builtin_amdgcn_mfma_f32_16x16x32_bf16(qf[1][db], kf, s[1][kq], 0, 0, 0);
      }
    }
    __builtin_amdgcn_s_setprio(0);

    // ---- per q-set: fused softcap+exp (fixed max), P -> LDS, P-frags back
    bf8_t pf[2][2];
    #pragma unroll
    for (int s2 = 0; s2 < 2; ++s2) {
      #pragma unroll
      for (int kq = 0; kq < 4; ++kq) {
        const bool valid = (kb + kq * 16 + lo) < lenk;
        #pragma unroll
        for (int r = 0; r < 4; ++r) {
          const float e2 = __expf(s[s2][kq][r] * c2n);
          float p = __expf(-40.0f * __builtin_amdgcn_rcpf(e2 + 1.0f));
          p = valid ? p : 0.0f;
          lp[s2][r] += p;
          pw[(4 * gp + r) * 72 + kq * 16 + lo] = f2bf(p);
        }
      }
      asm volatile("s_waitcnt lgkmcnt(0)" ::: "memory");
      __builtin_amdgcn_sched_barrier(0);
      pf[s2][0] = *(const bf8_t*)(pw + lo * 72 + gp * 8);
      pf[s2][1] = *(const bf8_t*)(pw + lo * 72 + 32 + gp * 8);
      // (DS pipe is in-order per wave: set1's overwrites cannot pass these reads)
    }

    // ---- PV: each vf read feeds both q-sets' MFMAs
    __builtin_amdgcn_s_setprio(1);
    #pragma unroll
    for (int ks = 0; ks < 2; ++ks) {
      #pragma unroll
      for (int nt = 0; nt < 8; ++nt) {
        const int d = nt * 16 + lo;
        const bf8_t vf = *(const bf8_t*)(
            vtb + d * 144 + (((4 * ks + gp) ^ ((2 * nt + (lo >> 3)) & 7)) << 4));
        acc[0][nt] = __builtin_amdgcn_mfma_f32_16x16x32_bf16(pf[0][ks], vf, acc[0][nt], 0, 0, 0);
        acc[1][nt] = __builtin_amdgcn_mfma_f32_16x16x32_bf16(pf[1][ks], vf, acc[1][nt], 0, 0, 0);
      }
    }
    __builtin_amdgcn_s_setprio(0);

    // land tile kt+1 into the other buffer, then one barrier
    if (kt + 1 < nkt) write_tile((kt + 1) & 1);
    __syncthreads();
  }

  // ---- epilogue: reduce l across the 16 lanes of each group, then O = acc/l
  #pragma unroll
  for (int s2 = 0; s2 < 2; ++s2) {
    #pragma unroll
    for (int off = 1; off < 16; off <<= 1) {
      #pragma unroll
      for (int r = 0; r < 4; ++r) lp[s2][r] += __shfl_xor(lp[s2][r], off, 16);
    }
    #pragma unroll
    for (int r = 0; r < 4; ++r) {
      const int qr = qrow_base + s2 * 16 + 4 * gp + r;
      if (qr < lenq) {
        const float inv_l = 1.0f / lp[s2][r];
        float* op = O + ((size_t)(q0 + qr) * H_ + h) * D_;
        #pragma unroll
        for (int nt = 0; nt < 8; ++nt)
          op[nt * 16 + lo] = acc[s2][nt][r] * inv_l;
      }
    }
  }
}

extern "C" void kernel_launch(void* const* d_in, const int* in_sizes, int n_in,
                              void* d_out, int out_size, void* d_ws, size_t ws_size,
                              hipStream_t stream) {
  const float* Q  = (const float*)d_in[0];
  const float* K  = (const float*)d_in[1];
  const float* V  = (const float*)d_in[2];
  const int* cuq  = (const int*)d_in[3];
  const int* cuk  = (const int*)d_in[4];
  float* out      = (float*)d_out;
  const int B = in_sizes[3] - 1;
  dim3 grid(B * 8, H_);                   // 8 = 1024 / QBLK(128)
  fa_varlen_kernel<<<grid, 256, 0, stream>>>(Q, K, V, cuq, cuk, out);
}